// Round 1
// baseline (445.470 us; speedup 1.0000x reference)
//
#include <hip/hip_runtime.h>
#include <stdint.h>

#define D_MODEL 768
#define N3      2304
#define NHEAD   8
#define DH      96
#define BATCH   8
#define SEQ     4096
#define ROWS    (BATCH*SEQ)   // 32768
#define LN_EPS  1e-5f

typedef __attribute__((ext_vector_type(8))) __bf16 bf16x8;
typedef __attribute__((ext_vector_type(4))) float f32x4;
typedef __attribute__((ext_vector_type(8))) unsigned short ushort8;
typedef __attribute__((ext_vector_type(4))) unsigned short ushort4v;

__device__ __forceinline__ unsigned short f2bf(float f) {
  union { float f; unsigned int u; } v; v.f = f;
  unsigned int r = v.u + 0x7FFFu + ((v.u >> 16) & 1u);
  return (unsigned short)(r >> 16);
}
__device__ __forceinline__ float bf2f(unsigned short u) {
  union { unsigned int u; float f; } v; v.u = ((unsigned int)u) << 16;
  return v.f;
}

#define GLOBAL_LDS16(src, dst) \
  __builtin_amdgcn_global_load_lds((const __attribute__((address_space(1))) void*)(src), \
                                   (__attribute__((address_space(3))) void*)(dst), 16, 0, 0)

// ---------------- transpose + cast fp32[R][C] -> bf16[C][R] ----------------
__global__ __launch_bounds__(256) void transpose_cast_kernel(
    const float* __restrict__ in, unsigned short* __restrict__ out, int R, int C) {
  __shared__ float tile[32][33];
  int c0 = blockIdx.x * 32, r0 = blockIdx.y * 32;
  int tx = threadIdx.x & 31, ty = threadIdx.x >> 5;
  #pragma unroll
  for (int i = ty; i < 32; i += 8)
    tile[i][tx] = in[(size_t)(r0 + i) * C + c0 + tx];
  __syncthreads();
  #pragma unroll
  for (int i = ty; i < 32; i += 8)
    out[(size_t)(c0 + i) * R + r0 + tx] = f2bf(tile[tx][i]);
}

// ---------------- LayerNorm: fp32 in -> bf16 out, one wave per row ----------------
__global__ __launch_bounds__(256) void ln_kernel(
    const float* __restrict__ x, const float* __restrict__ gamma,
    const float* __restrict__ beta, unsigned short* __restrict__ xn) {
  int wave = threadIdx.x >> 6, lane = threadIdx.x & 63;
  int row = blockIdx.x * 4 + wave;
  const float* xr = x + (size_t)row * D_MODEL;
  f32x4 v[3];
  float s = 0.f, sq = 0.f;
  #pragma unroll
  for (int i = 0; i < 3; ++i) {
    v[i] = *(const f32x4*)(xr + (i * 64 + lane) * 4);
    #pragma unroll
    for (int c = 0; c < 4; ++c) { s += v[i][c]; sq += v[i][c] * v[i][c]; }
  }
  #pragma unroll
  for (int o = 32; o; o >>= 1) {
    s  += __shfl_xor(s, o, 64);
    sq += __shfl_xor(sq, o, 64);
  }
  float mu  = s * (1.f / 768.f);
  float var = sq * (1.f / 768.f) - mu * mu;
  float rs  = rsqrtf(var + LN_EPS);
  #pragma unroll
  for (int i = 0; i < 3; ++i) {
    int col = (i * 64 + lane) * 4;
    ushort4v o;
    #pragma unroll
    for (int c = 0; c < 4; ++c)
      o[c] = f2bf((v[i][c] - mu) * rs * gamma[col + c] + beta[col + c]);
    *(ushort4v*)(xn + (size_t)row * D_MODEL + col) = o;
  }
}

// ---------------- GEMM: C[M][N] = A[M][K] @ Bt[N][K]^T  (m97 structure) ----------------
// EPI 0: qkv epilogue (elu+1 on cols<1536), bf16 out.  EPI 1: +residual, fp32 out.
template <int EPI>
__global__ __launch_bounds__(256) void gemm_kernel(
    const unsigned short* __restrict__ A, const unsigned short* __restrict__ Bt,
    int M, int N, int K, int nbn,
    unsigned short* __restrict__ Cb, const float* __restrict__ resid,
    float* __restrict__ Cf) {
  __shared__ unsigned short As[128][64];
  __shared__ unsigned short Bs[128][64];
  int bn = blockIdx.x % nbn, bm = blockIdx.x / nbn;
  int wave = threadIdx.x >> 6, lane = threadIdx.x & 63;
  int wm = wave >> 1, wn = wave & 1;
  f32x4 zero = {0.f, 0.f, 0.f, 0.f};
  f32x4 acc[4][4];
  #pragma unroll
  for (int i = 0; i < 4; ++i)
    #pragma unroll
    for (int j = 0; j < 4; ++j) acc[i][j] = zero;

  int lrow = lane >> 3, lcol = (lane & 7) * 8;
  for (int kt = 0; kt < K; kt += 64) {
    if (kt) __syncthreads();
    #pragma unroll
    for (int it = 0; it < 4; ++it) {
      int rb = wave * 4 + it;  // 0..15, wave-uniform
      const unsigned short* ga = A  + (size_t)(bm * 128 + rb * 8 + lrow) * K + kt + lcol;
      GLOBAL_LDS16(ga, &As[rb * 8][0]);
      const unsigned short* gb = Bt + (size_t)(bn * 128 + rb * 8 + lrow) * K + kt + lcol;
      GLOBAL_LDS16(gb, &Bs[rb * 8][0]);
    }
    __syncthreads();
    #pragma unroll
    for (int kk = 0; kk < 2; ++kk) {
      int k0 = kk * 32 + (lane >> 4) * 8;
      bf16x8 af[4], bfr[4];
      #pragma unroll
      for (int i = 0; i < 4; ++i) af[i]  = *(const bf16x8*)&As[wm * 64 + i * 16 + (lane & 15)][k0];
      #pragma unroll
      for (int j = 0; j < 4; ++j) bfr[j] = *(const bf16x8*)&Bs[wn * 64 + j * 16 + (lane & 15)][k0];
      #pragma unroll
      for (int i = 0; i < 4; ++i)
        #pragma unroll
        for (int j = 0; j < 4; ++j)
          acc[i][j] = __builtin_amdgcn_mfma_f32_16x16x32_bf16(af[i], bfr[j], acc[i][j], 0, 0, 0);
    }
  }
  int r0 = bm * 128 + wm * 64 + (lane >> 4) * 4;
  int c0 = bn * 128 + wn * 64 + (lane & 15);
  #pragma unroll
  for (int i = 0; i < 4; ++i) {
    #pragma unroll
    for (int j = 0; j < 4; ++j) {
      int col = c0 + j * 16;
      #pragma unroll
      for (int r = 0; r < 4; ++r) {
        int row = r0 + i * 16 + r;
        float v = acc[i][j][r];
        if (EPI == 0) {
          if (col < 1536) v = (v > 0.f) ? v + 1.f : __expf(v);  // elu(x)+1
          Cb[(size_t)row * N + col] = f2bf(v);
        } else {
          Cf[(size_t)row * N + col] = v + resid[(size_t)row * N + col];
        }
      }
    }
  }
}

// ---------------- kv aggregation: per (b,h) partial kv[96][96] + ksum[96] ----------------
// grid 512 = 64 bh * 8 chunks of 512 l's; each chunk in 4 sub-tiles of 128.
__global__ __launch_bounds__(256) void kvagg_kernel(
    const unsigned short* __restrict__ qkv,
    float* __restrict__ kvp, float* __restrict__ ksump) {
  __shared__ unsigned short KT[96][136];
  __shared__ unsigned short VT[96][136];
  int bh = blockIdx.x >> 3, chunk = blockIdx.x & 7;
  int b = bh >> 3, h = bh & 7;
  int wave = threadIdx.x >> 6, lane = threadIdx.x & 63;
  int wm = wave >> 1, wn = wave & 1;
  size_t rowbase = (size_t)b * SEQ;
  int ck = D_MODEL + h * DH, cv = 2 * D_MODEL + h * DH;
  f32x4 zero = {0.f, 0.f, 0.f, 0.f};
  f32x4 acc[3][3];
  #pragma unroll
  for (int i = 0; i < 3; ++i)
    #pragma unroll
    for (int j = 0; j < 3; ++j) acc[i][j] = zero;
  float ks = 0.f;

  for (int s = 0; s < 4; ++s) {
    int l0 = chunk * 512 + s * 128;
    if (s) __syncthreads();
    #pragma unroll
    for (int i = 0; i < 6; ++i) {
      int idx = i * 256 + threadIdx.x;   // 0..1535
      int l = idx / 12, oc = idx % 12;
      size_t g = (rowbase + l0 + l) * N3;
      ushort8 kk = *(const ushort8*)(qkv + g + ck + oc * 8);
      ushort8 vv = *(const ushort8*)(qkv + g + cv + oc * 8);
      #pragma unroll
      for (int j = 0; j < 8; ++j) { KT[oc * 8 + j][l] = kk[j]; VT[oc * 8 + j][l] = vv[j]; }
    }
    __syncthreads();
    if (threadIdx.x < 96) {
      #pragma unroll 8
      for (int l = 0; l < 128; ++l) ks += bf2f(KT[threadIdx.x][l]);
    }
    #pragma unroll
    for (int kq = 0; kq < 4; ++kq) {
      int k0 = kq * 32 + (lane >> 4) * 8;
      bf16x8 af[3], bfv[3];
      #pragma unroll
      for (int i = 0; i < 3; ++i) af[i]  = *(const bf16x8*)&KT[wm * 48 + i * 16 + (lane & 15)][k0];
      #pragma unroll
      for (int j = 0; j < 3; ++j) bfv[j] = *(const bf16x8*)&VT[wn * 48 + j * 16 + (lane & 15)][k0];
      #pragma unroll
      for (int i = 0; i < 3; ++i)
        #pragma unroll
        for (int j = 0; j < 3; ++j)
          acc[i][j] = __builtin_amdgcn_mfma_f32_16x16x32_bf16(af[i], bfv[j], acc[i][j], 0, 0, 0);
    }
  }
  float* kvpp = kvp + (size_t)blockIdx.x * (96 * 96);
  #pragma unroll
  for (int i = 0; i < 3; ++i)
    #pragma unroll
    for (int j = 0; j < 3; ++j)
      #pragma unroll
      for (int r = 0; r < 4; ++r) {
        int d = wm * 48 + i * 16 + (lane >> 4) * 4 + r;
        int e = wn * 48 + j * 16 + (lane & 15);
        kvpp[d * 96 + e] = acc[i][j][r];
      }
  if (threadIdx.x < 96) ksump[(size_t)blockIdx.x * 96 + threadIdx.x] = ks;
}

// ---------------- reduce 8 partials -> kvT bf16 [64][112][96]; row96=ksum, rows 97..111=0 ----------------
__global__ __launch_bounds__(256) void kvreduce_kernel(
    const float* __restrict__ kvp, const float* __restrict__ ksump,
    unsigned short* __restrict__ kvT) {
  int idx = blockIdx.x * 256 + threadIdx.x;
  if (idx >= 64 * 112 * 96) return;
  int d = idx % 96;
  int e = (idx / 96) % 112;
  int bh = idx / (96 * 112);
  float s = 0.f;
  if (e < 96) {
    #pragma unroll
    for (int c = 0; c < 8; ++c) s += kvp[(((size_t)bh * 8 + c) * 96 + d) * 96 + e];
  } else if (e == 96) {
    #pragma unroll
    for (int c = 0; c < 8; ++c) s += ksump[((size_t)bh * 8 + c) * 96 + d];
  }
  kvT[idx] = f2bf(s);
}

// ---------------- readout: attn[l][h*96+e] = (q[l]@kv)[e] / max(q[l]@ksum,1e-6) ----------------
// grid 2048 = 64 bh * 32 chunks of 128 rows; wave handles 32 rows x 112 cols.
__global__ __launch_bounds__(256) void readout_kernel(
    const unsigned short* __restrict__ qkv, const unsigned short* __restrict__ kvT,
    unsigned short* __restrict__ attn) {
  __shared__ unsigned short Qs[128][104];
  __shared__ unsigned short Ks[112][104];
  int bh = blockIdx.x >> 5, lc = blockIdx.x & 31;
  int b = bh >> 3, h = bh & 7;
  int l0 = lc * 128;
  int wave = threadIdx.x >> 6, lane = threadIdx.x & 63;
  #pragma unroll
  for (int i = 0; i < 6; ++i) {
    int idx = i * 256 + threadIdx.x;   // 0..1535
    int l = idx / 12, oc = idx % 12;
    size_t g = ((size_t)b * SEQ + l0 + l) * N3 + h * DH + oc * 8;
    *(ushort8*)&Qs[l][oc * 8] = *(const ushort8*)(qkv + g);
  }
  const unsigned short* kvbh = kvT + (size_t)bh * 112 * 96;
  #pragma unroll
  for (int i = 0; i < 6; ++i) {
    int idx = i * 256 + threadIdx.x;
    if (idx < 1344) {
      int e = idx / 12, oc = idx % 12;
      *(ushort8*)&Ks[e][oc * 8] = *(const ushort8*)(kvbh + e * 96 + oc * 8);
    }
  }
  __syncthreads();
  f32x4 zero = {0.f, 0.f, 0.f, 0.f};
  f32x4 acc[2][7];
  #pragma unroll
  for (int i = 0; i < 2; ++i)
    #pragma unroll
    for (int j = 0; j < 7; ++j) acc[i][j] = zero;
  #pragma unroll
  for (int kq = 0; kq < 3; ++kq) {
    int k0 = kq * 32 + (lane >> 4) * 8;
    bf16x8 af[2], bfv[7];
    #pragma unroll
    for (int i = 0; i < 2; ++i) af[i]  = *(const bf16x8*)&Qs[wave * 32 + i * 16 + (lane & 15)][k0];
    #pragma unroll
    for (int j = 0; j < 7; ++j) bfv[j] = *(const bf16x8*)&Ks[j * 16 + (lane & 15)][k0];
    #pragma unroll
    for (int i = 0; i < 2; ++i)
      #pragma unroll
      for (int j = 0; j < 7; ++j)
        acc[i][j] = __builtin_amdgcn_mfma_f32_16x16x32_bf16(af[i], bfv[j], acc[i][j], 0, 0, 0);
  }
  int g4 = lane >> 4;
  #pragma unroll
  for (int i = 0; i < 2; ++i) {
    #pragma unroll
    for (int r = 0; r < 4; ++r) {
      float nv = __shfl(acc[i][6][r], lane & 48, 64);   // col 96 value for this row
      float inv = 1.f / fmaxf(nv, 1e-6f);
      size_t orow = (size_t)b * SEQ + l0 + wave * 32 + i * 16 + g4 * 4 + r;
      #pragma unroll
      for (int j = 0; j < 6; ++j) {
        int col = h * DH + j * 16 + (lane & 15);
        attn[orow * D_MODEL + col] = f2bf(acc[i][j][r] * inv);
      }
    }
  }
}

extern "C" void kernel_launch(void* const* d_in, const int* in_sizes, int n_in,
                              void* d_out, int out_size, void* d_ws, size_t ws_size,
                              hipStream_t stream) {
  const float* x     = (const float*)d_in[0];
  const float* gamma = (const float*)d_in[1];
  const float* beta  = (const float*)d_in[2];
  const float* w_qkv = (const float*)d_in[3];
  const float* w_out = (const float*)d_in[4];
  float* out = (float*)d_out;

  char* ws = (char*)d_ws;
  size_t off = 0;
  auto alloc = [&](size_t bytes) -> void* {
    void* p = ws + off; off += (bytes + 255) & ~(size_t)255; return p;
  };
  unsigned short* xn    = (unsigned short*)alloc((size_t)ROWS * D_MODEL * 2);  // reused as attn
  unsigned short* qkv   = (unsigned short*)alloc((size_t)ROWS * N3 * 2);
  unsigned short* wqkvT = (unsigned short*)alloc((size_t)N3 * D_MODEL * 2);
  unsigned short* woutT = (unsigned short*)alloc((size_t)D_MODEL * D_MODEL * 2);
  float* kvp            = (float*)alloc((size_t)512 * 96 * 96 * 4);
  float* ksump          = (float*)alloc((size_t)512 * 96 * 4);
  unsigned short* kvT   = (unsigned short*)alloc((size_t)64 * 112 * 96 * 2);

  transpose_cast_kernel<<<dim3(N3 / 32, D_MODEL / 32), 256, 0, stream>>>(w_qkv, wqkvT, D_MODEL, N3);
  transpose_cast_kernel<<<dim3(D_MODEL / 32, D_MODEL / 32), 256, 0, stream>>>(w_out, woutT, D_MODEL, D_MODEL);
  ln_kernel<<<ROWS / 4, 256, 0, stream>>>(x, gamma, beta, xn);
  gemm_kernel<0><<<(ROWS / 128) * (N3 / 128), 256, 0, stream>>>(
      xn, wqkvT, ROWS, N3, D_MODEL, N3 / 128, qkv, nullptr, nullptr);
  kvagg_kernel<<<512, 256, 0, stream>>>(qkv, kvp, ksump);
  kvreduce_kernel<<<(64 * 112 * 96 + 255) / 256, 256, 0, stream>>>(kvp, ksump, kvT);
  readout_kernel<<<2048, 256, 0, stream>>>(qkv, kvT, xn);  // attn overwrites xn
  gemm_kernel<1><<<(ROWS / 128) * (D_MODEL / 128), 256, 0, stream>>>(
      xn, woutT, ROWS, D_MODEL, D_MODEL, D_MODEL / 128, nullptr, x, out);
}

// Round 2
// 399.339 us; speedup vs baseline: 1.1155x; 1.1155x over previous
//
#include <hip/hip_runtime.h>
#include <stdint.h>

#define D_MODEL 768
#define N3      2304
#define NHEAD   8
#define DH      96
#define BATCH   8
#define SEQ     4096
#define ROWS    (BATCH*SEQ)   // 32768
#define LN_EPS  1e-5f

typedef __attribute__((ext_vector_type(8))) __bf16 bf16x8;
typedef __attribute__((ext_vector_type(4))) float f32x4;
typedef __attribute__((ext_vector_type(8))) unsigned short ushort8;
typedef __attribute__((ext_vector_type(4))) unsigned short ushort4v;

__device__ __forceinline__ unsigned short f2bf(float f) {
  union { float f; unsigned int u; } v; v.f = f;
  unsigned int r = v.u + 0x7FFFu + ((v.u >> 16) & 1u);
  return (unsigned short)(r >> 16);
}
__device__ __forceinline__ float bf2f(unsigned short u) {
  union { unsigned int u; float f; } v; v.u = ((unsigned int)u) << 16;
  return v.f;
}

#define GLOBAL_LDS16(src, dst) \
  __builtin_amdgcn_global_load_lds((const __attribute__((address_space(1))) void*)(src), \
                                   (__attribute__((address_space(3))) void*)(dst), 16, 0, 0)

#define BAR2() do { asm volatile("" ::: "memory"); __builtin_amdgcn_s_barrier(); \
                    asm volatile("" ::: "memory"); } while (0)
#define GATE(n) do { asm volatile("s_waitcnt vmcnt(" #n ")" ::: "memory"); \
                     __builtin_amdgcn_s_barrier(); asm volatile("" ::: "memory"); } while (0)

// ---------------- transpose + cast fp32[R][C] -> bf16[C][R] ----------------
__global__ __launch_bounds__(256) void transpose_cast_kernel(
    const float* __restrict__ in, unsigned short* __restrict__ out, int R, int C) {
  __shared__ float tile[32][33];
  int c0 = blockIdx.x * 32, r0 = blockIdx.y * 32;
  int tx = threadIdx.x & 31, ty = threadIdx.x >> 5;
  #pragma unroll
  for (int i = ty; i < 32; i += 8)
    tile[i][tx] = in[(size_t)(r0 + i) * C + c0 + tx];
  __syncthreads();
  #pragma unroll
  for (int i = ty; i < 32; i += 8)
    out[(size_t)(c0 + i) * R + r0 + tx] = f2bf(tile[tx][i]);
}

// ---------------- LayerNorm: fp32 in -> bf16 out, one wave per row ----------------
__global__ __launch_bounds__(256) void ln_kernel(
    const float* __restrict__ x, const float* __restrict__ gamma,
    const float* __restrict__ beta, unsigned short* __restrict__ xn) {
  int wave = threadIdx.x >> 6, lane = threadIdx.x & 63;
  int row = blockIdx.x * 4 + wave;
  const float* xr = x + (size_t)row * D_MODEL;
  f32x4 v[3];
  float s = 0.f, sq = 0.f;
  #pragma unroll
  for (int i = 0; i < 3; ++i) {
    v[i] = *(const f32x4*)(xr + (i * 64 + lane) * 4);
    #pragma unroll
    for (int c = 0; c < 4; ++c) { s += v[i][c]; sq += v[i][c] * v[i][c]; }
  }
  #pragma unroll
  for (int o = 32; o; o >>= 1) {
    s  += __shfl_xor(s, o, 64);
    sq += __shfl_xor(sq, o, 64);
  }
  float mu  = s * (1.f / 768.f);
  float var = sq * (1.f / 768.f) - mu * mu;
  float rs  = rsqrtf(var + LN_EPS);
  #pragma unroll
  for (int i = 0; i < 3; ++i) {
    int col = (i * 64 + lane) * 4;
    ushort4v o;
    #pragma unroll
    for (int c = 0; c < 4; ++c)
      o[c] = f2bf((v[i][c] - mu) * rs * gamma[col + c] + beta[col + c]);
    *(ushort4v*)(xn + (size_t)row * D_MODEL + col) = o;
  }
}

// ============ GEMM 256x256, BK=64, 8 waves, 8-phase deep pipeline ============
// C[M][N] = A[M][K] @ Bt[N][K]^T.  EPI 0: elu+1 on cols<1536, bf16 out.
// EPI 1: +residual, fp32 out.
// LDS: As/Bs = 2 bufs x (256x64) bf16 each = 128 KiB total. buf = ktile&1.
// A slot-set s (=qm) holds logical rows {wm*128 + s*64 .. +64 | wm=0,1} at
// lds rows [s*128, s*128+128); B slot-set s (=qn) holds Bt-rows
// {wn*64 + s*32 .. +32 | wn=0..3}. T2 swizzle: physical 16B-slot =
// logical_slot ^ (ldsrow&7), same involution on stage-source & read.
template <int EPI>
__global__ __launch_bounds__(512, 2) void gemm2_kernel(
    const unsigned short* __restrict__ A, const unsigned short* __restrict__ Bt,
    int M, int N, int K, int nbn,
    unsigned short* __restrict__ Cb, const float* __restrict__ resid,
    float* __restrict__ Cf) {
  __shared__ unsigned short As[32768];  // [buf:2][256][64]
  __shared__ unsigned short Bs[32768];

  const int NKT = K >> 6;               // K-tiles (must be even)
  // XCD-chunked swizzle (grid % 8 == 0)
  int nwg = gridDim.x, id = blockIdx.x;
  int q8 = nwg >> 3;
  int wg = (id & 7) * q8 + (id >> 3);
  int bm = wg / nbn, bn = wg % nbn;

  const int lane = threadIdx.x & 63, wid = threadIdx.x >> 6;
  const int wm = wid >> 2, wn = wid & 3;
  const int l15 = lane & 15, hi = lane >> 4;
  // read-side swizzled column (shorts): logical slot (ks*4+hi) ^ (row&7)
  const int colS0 = ((hi ^ (lane & 7)) << 3);   // ks=0; ks=1 = idx ^ 32
  // stage-side per-lane: row sub-index & swizzled source column (bytes)
  const int su  = lane >> 3;                      // ldsrow&7 for this lane
  const int scb = ((lane & 7) ^ su) << 4;         // swizzled byte col in [0,128)

  auto stageA = [&](int buf, int s, int kt) {
    #pragma unroll
    for (int q = 0; q < 2; ++q) {
      int u = q * 64 + wid * 8 + su;              // lds row within buf-half pair
      int rho = ((u >> 6) << 7) | (s << 6) | (u & 63);
      const unsigned short* src = A + (size_t)(bm * 256 + rho) * K + kt * 64 + (scb >> 1);
      GLOBAL_LDS16(src, &As[buf * 16384 + s * 8192 + q * 4096 + wid * 512]);
    }
  };
  auto stageB = [&](int buf, int s, int kt) {
    #pragma unroll
    for (int q = 0; q < 2; ++q) {
      int u = q * 64 + wid * 8 + su;
      int rho = ((u >> 5) << 6) | (s << 5) | (u & 31);
      const unsigned short* src = Bt + (size_t)(bn * 256 + rho) * K + kt * 64 + (scb >> 1);
      GLOBAL_LDS16(src, &Bs[buf * 16384 + s * 8192 + q * 4096 + wid * 512]);
    }
  };

  f32x4 acc[2][4][2][2];   // [qm][mf][qn][nf]
  #pragma unroll
  for (int a = 0; a < 2; ++a)
    #pragma unroll
    for (int b = 0; b < 4; ++b)
      #pragma unroll
      for (int c = 0; c < 2; ++c)
        #pragma unroll
        for (int d = 0; d < 2; ++d) acc[a][b][c][d] = (f32x4){0.f, 0.f, 0.f, 0.f};

  // Prologue: buf0 <- K0 (B0,A0,A1,B1), buf1 <- K1 (B0,A0). Gate: last 2 sets in flight.
  stageB(0, 0, 0); stageA(0, 0, 0); stageA(0, 1, 0); stageB(0, 1, 0);
  stageB(1, 0, 1); stageA(1, 0, 1);
  GATE(4);

#define PHASE(BUF, QM, QN, STG, ENDSYNC) \
  { bf16x8 af[4][2], bv[2][2]; \
    _Pragma("unroll") for (int mf = 0; mf < 4; ++mf) { \
      int ia = (BUF) * 16384 + ((QM) * 128 + wm * 64 + mf * 16 + l15) * 64 + colS0; \
      af[mf][0] = *(const bf16x8*)&As[ia]; \
      af[mf][1] = *(const bf16x8*)&As[ia ^ 32]; } \
    _Pragma("unroll") for (int nf = 0; nf < 2; ++nf) { \
      int ib = (BUF) * 16384 + ((QN) * 128 + wn * 32 + nf * 16 + l15) * 64 + colS0; \
      bv[nf][0] = *(const bf16x8*)&Bs[ib]; \
      bv[nf][1] = *(const bf16x8*)&Bs[ib ^ 32]; } \
    STG; \
    BAR2(); \
    __builtin_amdgcn_s_setprio(1); \
    _Pragma("unroll") for (int mf = 0; mf < 4; ++mf) \
      _Pragma("unroll") for (int nf = 0; nf < 2; ++nf) { \
        acc[QM][mf][QN][nf] = __builtin_amdgcn_mfma_f32_16x16x32_bf16( \
            af[mf][0], bv[nf][0], acc[QM][mf][QN][nf], 0, 0, 0); \
        acc[QM][mf][QN][nf] = __builtin_amdgcn_mfma_f32_16x16x32_bf16( \
            af[mf][1], bv[nf][1], acc[QM][mf][QN][nf], 0, 0, 0); } \
    __builtin_amdgcn_s_setprio(0); \
    ENDSYNC; }

  for (int it = 0; it < (NKT >> 1); ++it) {
    int T = 2 * it;
    bool g2 = (T + 2) < NKT, g3 = (T + 3) < NKT;
    PHASE(0, 0, 0, stageA(1, 1, T + 1),           BAR2());   // p0
    PHASE(0, 1, 0, stageB(1, 1, T + 1),           GATE(8));  // p1
    PHASE(0, 0, 1, if (g2) stageB(0, 0, T + 2),   BAR2());   // p2
    PHASE(0, 1, 1, if (g2) stageA(0, 0, T + 2),   GATE(6));  // p3
    PHASE(1, 0, 0, if (g2) stageA(0, 1, T + 2),   BAR2());   // p4
    PHASE(1, 1, 0, if (g2) stageB(0, 1, T + 2),   GATE(8));  // p5
    PHASE(1, 0, 1, if (g3) stageB(1, 0, T + 3),   BAR2());   // p6
    PHASE(1, 1, 1, if (g3) stageA(1, 0, T + 3),   GATE(4));  // p7
  }
#undef PHASE

  // Epilogue
  int r0 = bm * 256 + wm * 128, c0 = bn * 256 + wn * 64;
  #pragma unroll
  for (int qm = 0; qm < 2; ++qm)
    #pragma unroll
    for (int mf = 0; mf < 4; ++mf)
      #pragma unroll
      for (int qn = 0; qn < 2; ++qn)
        #pragma unroll
        for (int nf = 0; nf < 2; ++nf) {
          int col = c0 + qn * 32 + nf * 16 + l15;
          #pragma unroll
          for (int r = 0; r < 4; ++r) {
            int row = r0 + qm * 64 + mf * 16 + hi * 4 + r;
            float v = acc[qm][mf][qn][nf][r];
            if (EPI == 0) {
              if (col < 1536) v = (v > 0.f) ? v + 1.f : __expf(v);  // elu(x)+1
              Cb[(size_t)row * N + col] = f2bf(v);
            } else {
              Cf[(size_t)row * N + col] = v + resid[(size_t)row * N + col];
            }
          }
        }
}

// ---------------- kv aggregation: per (b,h) partial kv[96][96] + ksum[96] ----------------
__global__ __launch_bounds__(256) void kvagg_kernel(
    const unsigned short* __restrict__ qkv,
    float* __restrict__ kvp, float* __restrict__ ksump) {
  __shared__ unsigned short KT[96][136];
  __shared__ unsigned short VT[96][136];
  int bh = blockIdx.x >> 3, chunk = blockIdx.x & 7;
  int b = bh >> 3, h = bh & 7;
  int wave = threadIdx.x >> 6, lane = threadIdx.x & 63;
  int wm = wave >> 1, wn = wave & 1;
  size_t rowbase = (size_t)b * SEQ;
  int ck = D_MODEL + h * DH, cv = 2 * D_MODEL + h * DH;
  f32x4 zero = {0.f, 0.f, 0.f, 0.f};
  f32x4 acc[3][3];
  #pragma unroll
  for (int i = 0; i < 3; ++i)
    #pragma unroll
    for (int j = 0; j < 3; ++j) acc[i][j] = zero;
  float ks = 0.f;

  for (int s = 0; s < 4; ++s) {
    int l0 = chunk * 512 + s * 128;
    if (s) __syncthreads();
    #pragma unroll
    for (int i = 0; i < 6; ++i) {
      int idx = i * 256 + threadIdx.x;   // 0..1535
      int l = idx / 12, oc = idx % 12;
      size_t g = (rowbase + l0 + l) * N3;
      ushort8 kk = *(const ushort8*)(qkv + g + ck + oc * 8);
      ushort8 vv = *(const ushort8*)(qkv + g + cv + oc * 8);
      #pragma unroll
      for (int j = 0; j < 8; ++j) { KT[oc * 8 + j][l] = kk[j]; VT[oc * 8 + j][l] = vv[j]; }
    }
    __syncthreads();
    if (threadIdx.x < 96) {
      #pragma unroll 8
      for (int l = 0; l < 128; ++l) ks += bf2f(KT[threadIdx.x][l]);
    }
    #pragma unroll
    for (int kq = 0; kq < 4; ++kq) {
      int k0 = kq * 32 + (lane >> 4) * 8;
      bf16x8 af[3], bfv[3];
      #pragma unroll
      for (int i = 0; i < 3; ++i) af[i]  = *(const bf16x8*)&KT[wm * 48 + i * 16 + (lane & 15)][k0];
      #pragma unroll
      for (int j = 0; j < 3; ++j) bfv[j] = *(const bf16x8*)&VT[wn * 48 + j * 16 + (lane & 15)][k0];
      #pragma unroll
      for (int i = 0; i < 3; ++i)
        #pragma unroll
        for (int j = 0; j < 3; ++j)
          acc[i][j] = __builtin_amdgcn_mfma_f32_16x16x32_bf16(af[i], bfv[j], acc[i][j], 0, 0, 0);
    }
  }
  float* kvpp = kvp + (size_t)blockIdx.x * (96 * 96);
  #pragma unroll
  for (int i = 0; i < 3; ++i)
    #pragma unroll
    for (int j = 0; j < 3; ++j)
      #pragma unroll
      for (int r = 0; r < 4; ++r) {
        int d = wm * 48 + i * 16 + (lane >> 4) * 4 + r;
        int e = wn * 48 + j * 16 + (lane & 15);
        kvpp[d * 96 + e] = acc[i][j][r];
      }
  if (threadIdx.x < 96) ksump[(size_t)blockIdx.x * 96 + threadIdx.x] = ks;
}

// ---------------- reduce 8 partials -> kvT bf16 [64][112][96] ----------------
__global__ __launch_bounds__(256) void kvreduce_kernel(
    const float* __restrict__ kvp, const float* __restrict__ ksump,
    unsigned short* __restrict__ kvT) {
  int idx = blockIdx.x * 256 + threadIdx.x;
  if (idx >= 64 * 112 * 96) return;
  int d = idx % 96;
  int e = (idx / 96) % 112;
  int bh = idx / (96 * 112);
  float s = 0.f;
  if (e < 96) {
    #pragma unroll
    for (int c = 0; c < 8; ++c) s += kvp[(((size_t)bh * 8 + c) * 96 + d) * 96 + e];
  } else if (e == 96) {
    #pragma unroll
    for (int c = 0; c < 8; ++c) s += ksump[((size_t)bh * 8 + c) * 96 + d];
  }
  kvT[idx] = f2bf(s);
}

// ---------------- readout ----------------
__global__ __launch_bounds__(256) void readout_kernel(
    const unsigned short* __restrict__ qkv, const unsigned short* __restrict__ kvT,
    unsigned short* __restrict__ attn) {
  __shared__ unsigned short Qs[128][104];
  __shared__ unsigned short Ks[112][104];
  int bh = blockIdx.x >> 5, lc = blockIdx.x & 31;
  int b = bh >> 3, h = bh & 7;
  int l0 = lc * 128;
  int wave = threadIdx.x >> 6, lane = threadIdx.x & 63;
  #pragma unroll
  for (int i = 0; i < 6; ++i) {
    int idx = i * 256 + threadIdx.x;   // 0..1535
    int l = idx / 12, oc = idx % 12;
    size_t g = ((size_t)b * SEQ + l0 + l) * N3 + h * DH + oc * 8;
    *(ushort8*)&Qs[l][oc * 8] = *(const ushort8*)(qkv + g);
  }
  const unsigned short* kvbh = kvT + (size_t)bh * 112 * 96;
  #pragma unroll
  for (int i = 0; i < 6; ++i) {
    int idx = i * 256 + threadIdx.x;
    if (idx < 1344) {
      int e = idx / 12, oc = idx % 12;
      *(ushort8*)&Ks[e][oc * 8] = *(const ushort8*)(kvbh + e * 96 + oc * 8);
    }
  }
  __syncthreads();
  f32x4 zero = {0.f, 0.f, 0.f, 0.f};
  f32x4 acc[2][7];
  #pragma unroll
  for (int i = 0; i < 2; ++i)
    #pragma unroll
    for (int j = 0; j < 7; ++j) acc[i][j] = zero;
  #pragma unroll
  for (int kq = 0; kq < 3; ++kq) {
    int k0 = kq * 32 + (lane >> 4) * 8;
    bf16x8 af[2], bfv[7];
    #pragma unroll
    for (int i = 0; i < 2; ++i) af[i]  = *(const bf16x8*)&Qs[wave * 32 + i * 16 + (lane & 15)][k0];
    #pragma unroll
    for (int j = 0; j < 7; ++j) bfv[j] = *(const bf16x8*)&Ks[j * 16 + (lane & 15)][k0];
    #pragma unroll
    for (int i = 0; i < 2; ++i)
      #pragma unroll
      for (int j = 0; j < 7; ++j)
        acc[i][j] = __builtin_amdgcn_mfma_f32_16x16x32_bf16(af[i], bfv[j], acc[i][j], 0, 0, 0);
  }
  int g4 = lane >> 4;
  #pragma unroll
  for (int i = 0; i < 2; ++i) {
    #pragma unroll
    for (int r = 0; r < 4; ++r) {
      float nv = __shfl(acc[i][6][r], lane & 48, 64);   // col 96 value for this row
      float inv = 1.f / fmaxf(nv, 1e-6f);
      size_t orow = (size_t)b * SEQ + l0 + wave * 32 + i * 16 + g4 * 4 + r;
      #pragma unroll
      for (int j = 0; j < 6; ++j) {
        int col = h * DH + j * 16 + (lane & 15);
        attn[orow * D_MODEL + col] = f2bf(acc[i][j][r] * inv);
      }
    }
  }
}

extern "C" void kernel_launch(void* const* d_in, const int* in_sizes, int n_in,
                              void* d_out, int out_size, void* d_ws, size_t ws_size,
                              hipStream_t stream) {
  const float* x     = (const float*)d_in[0];
  const float* gamma = (const float*)d_in[1];
  const float* beta  = (const float*)d_in[2];
  const float* w_qkv = (const float*)d_in[3];
  const float* w_out = (const float*)d_in[4];
  float* out = (float*)d_out;

  char* ws = (char*)d_ws;
  size_t off = 0;
  auto alloc = [&](size_t bytes) -> void* {
    void* p = ws + off; off += (bytes + 255) & ~(size_t)255; return p;
  };
  unsigned short* xn    = (unsigned short*)alloc((size_t)ROWS * D_MODEL * 2);  // reused as attn
  unsigned short* qkv   = (unsigned short*)alloc((size_t)ROWS * N3 * 2);
  unsigned short* wqkvT = (unsigned short*)alloc((size_t)N3 * D_MODEL * 2);
  unsigned short* woutT = (unsigned short*)alloc((size_t)D_MODEL * D_MODEL * 2);
  float* kvp            = (float*)alloc((size_t)512 * 96 * 96 * 4);
  float* ksump          = (float*)alloc((size_t)512 * 96 * 4);
  unsigned short* kvT   = (unsigned short*)alloc((size_t)64 * 112 * 96 * 2);

  transpose_cast_kernel<<<dim3(N3 / 32, D_MODEL / 32), 256, 0, stream>>>(w_qkv, wqkvT, D_MODEL, N3);
  transpose_cast_kernel<<<dim3(D_MODEL / 32, D_MODEL / 32), 256, 0, stream>>>(w_out, woutT, D_MODEL, D_MODEL);
  ln_kernel<<<ROWS / 4, 256, 0, stream>>>(x, gamma, beta, xn);
  gemm2_kernel<0><<<(ROWS / 256) * (N3 / 256), 512, 0, stream>>>(
      xn, wqkvT, ROWS, N3, D_MODEL, N3 / 256, qkv, nullptr, nullptr);
  kvagg_kernel<<<512, 256, 0, stream>>>(qkv, kvp, ksump);
  kvreduce_kernel<<<(64 * 112 * 96 + 255) / 256, 256, 0, stream>>>(kvp, ksump, kvT);
  readout_kernel<<<2048, 256, 0, stream>>>(qkv, kvT, xn);  // attn overwrites xn
  gemm2_kernel<1><<<(ROWS / 256) * (D_MODEL / 256), 512, 0, stream>>>(
      xn, woutT, ROWS, D_MODEL, D_MODEL, D_MODEL / 256, nullptr, x, out);
}

// Round 3
// 391.930 us; speedup vs baseline: 1.1366x; 1.0189x over previous
//
#include <hip/hip_runtime.h>
#include <stdint.h>

#define D_MODEL 768
#define N3      2304
#define NHEAD   8
#define DH      96
#define BATCH   8
#define SEQ     4096
#define ROWS    (BATCH*SEQ)   // 32768
#define LN_EPS  1e-5f

typedef __attribute__((ext_vector_type(8))) __bf16 bf16x8;
typedef __attribute__((ext_vector_type(4))) float f32x4;
typedef __attribute__((ext_vector_type(8))) unsigned short ushort8;
typedef __attribute__((ext_vector_type(4))) unsigned short ushort4v;

__device__ __forceinline__ unsigned short f2bf(float f) {
  union { float f; unsigned int u; } v; v.f = f;
  unsigned int r = v.u + 0x7FFFu + ((v.u >> 16) & 1u);
  return (unsigned short)(r >> 16);
}
__device__ __forceinline__ float bf2f(unsigned short u) {
  union { unsigned int u; float f; } v; v.u = ((unsigned int)u) << 16;
  return v.f;
}

#define GLOBAL_LDS16(src, dst) \
  __builtin_amdgcn_global_load_lds((const __attribute__((address_space(1))) void*)(src), \
                                   (__attribute__((address_space(3))) void*)(dst), 16, 0, 0)

#define BAR2() do { asm volatile("" ::: "memory"); __builtin_amdgcn_s_barrier(); \
                    asm volatile("" ::: "memory"); } while (0)
#define GATE(n) do { asm volatile("s_waitcnt vmcnt(" #n ")" ::: "memory"); \
                     __builtin_amdgcn_s_barrier(); asm volatile("" ::: "memory"); } while (0)

// ---------------- transpose + cast fp32[R][C] -> bf16[C][R] ----------------
__global__ __launch_bounds__(256) void transpose_cast_kernel(
    const float* __restrict__ in, unsigned short* __restrict__ out, int R, int C) {
  __shared__ float tile[32][33];
  int c0 = blockIdx.x * 32, r0 = blockIdx.y * 32;
  int tx = threadIdx.x & 31, ty = threadIdx.x >> 5;
  #pragma unroll
  for (int i = ty; i < 32; i += 8)
    tile[i][tx] = in[(size_t)(r0 + i) * C + c0 + tx];
  __syncthreads();
  #pragma unroll
  for (int i = ty; i < 32; i += 8)
    out[(size_t)(c0 + i) * R + r0 + tx] = f2bf(tile[tx][i]);
}

// ---------------- LayerNorm: fp32 in -> bf16 out, one wave per row ----------------
__global__ __launch_bounds__(256) void ln_kernel(
    const float* __restrict__ x, const float* __restrict__ gamma,
    const float* __restrict__ beta, unsigned short* __restrict__ xn) {
  int wave = threadIdx.x >> 6, lane = threadIdx.x & 63;
  int row = blockIdx.x * 4 + wave;
  const float* xr = x + (size_t)row * D_MODEL;
  f32x4 v[3];
  float s = 0.f, sq = 0.f;
  #pragma unroll
  for (int i = 0; i < 3; ++i) {
    v[i] = *(const f32x4*)(xr + (i * 64 + lane) * 4);
    #pragma unroll
    for (int c = 0; c < 4; ++c) { s += v[i][c]; sq += v[i][c] * v[i][c]; }
  }
  #pragma unroll
  for (int o = 32; o; o >>= 1) {
    s  += __shfl_xor(s, o, 64);
    sq += __shfl_xor(sq, o, 64);
  }
  float mu  = s * (1.f / 768.f);
  float var = sq * (1.f / 768.f) - mu * mu;
  float rs  = rsqrtf(var + LN_EPS);
  #pragma unroll
  for (int i = 0; i < 3; ++i) {
    int col = (i * 64 + lane) * 4;
    ushort4v o;
    #pragma unroll
    for (int c = 0; c < 4; ++c)
      o[c] = f2bf((v[i][c] - mu) * rs * gamma[col + c] + beta[col + c]);
    *(ushort4v*)(xn + (size_t)row * D_MODEL + col) = o;
  }
}

// ============ GEMM 256x256, BK=64, 8 waves, 8-phase deep pipeline ============
// C[M][N] = A[M][K] @ Bt[N][K]^T.  EPI 0: elu+1 on cols<1536, bf16 out.
// EPI 1: +residual, fp32 out.
// LDS: As/Bs = 2 bufs x (256x64) bf16 each = 128 KiB total. buf = ktile&1.
// Per K-tile: 4 phases over C-quadrants (0,0)->(0,1)->(1,1)->(1,0); A-halves
// read once into af (overwritten at (1,1)), B-halves read once into bv0/bv1
// (held across the tile). 24 ds_read_b128/wave/K-tile (minimal).
// T2 swizzle: physical 16B-slot = logical_slot ^ (ldsrow&7), same involution
// on stage-source and read. Tail iteration peeled (no stages, GATE(0)).
template <int EPI>
__global__ __launch_bounds__(512, 2) void gemm2_kernel(
    const unsigned short* __restrict__ A, const unsigned short* __restrict__ Bt,
    int M, int N, int K, int nbn,
    unsigned short* __restrict__ Cb, const float* __restrict__ resid,
    float* __restrict__ Cf) {
  __shared__ unsigned short As[32768];  // [buf:2][set:2][128][64]
  __shared__ unsigned short Bs[32768];

  const int NKT = K >> 6;               // K-tiles (must be even, >=2)
  // XCD-chunked swizzle (grid % 8 == 0)
  int nwg = gridDim.x, id = blockIdx.x;
  int q8 = nwg >> 3;
  int wg = (id & 7) * q8 + (id >> 3);
  int bm = wg / nbn, bn = wg % nbn;

  const int lane = threadIdx.x & 63, wid = threadIdx.x >> 6;
  const int wm = wid >> 2, wn = wid & 3;
  const int l15 = lane & 15, hi = lane >> 4;
  // read-side swizzled column (shorts): logical 16B-slot (ks*4+hi) ^ (row&7)
  const int colS0 = ((hi ^ (lane & 7)) << 3);   // ks=0; ks=1 = index ^ 32
  // stage-side per-lane: row sub-index & swizzled source column (bytes)
  const int su  = lane >> 3;                      // ldsrow&7 for this lane
  const int scb = ((lane & 7) ^ su) << 4;         // swizzled byte col in [0,128)

  auto stageA = [&](int buf, int s, int kt) {
    #pragma unroll
    for (int q = 0; q < 2; ++q) {
      int u = q * 64 + wid * 8 + su;              // lds row within set
      int rho = ((u >> 6) << 7) | (s << 6) | (u & 63);
      const unsigned short* src = A + (size_t)(bm * 256 + rho) * K + kt * 64 + (scb >> 1);
      GLOBAL_LDS16(src, &As[buf * 16384 + s * 8192 + q * 4096 + wid * 512]);
    }
  };
  auto stageB = [&](int buf, int s, int kt) {
    #pragma unroll
    for (int q = 0; q < 2; ++q) {
      int u = q * 64 + wid * 8 + su;
      int rho = ((u >> 5) << 6) | (s << 5) | (u & 31);
      const unsigned short* src = Bt + (size_t)(bn * 256 + rho) * K + kt * 64 + (scb >> 1);
      GLOBAL_LDS16(src, &Bs[buf * 16384 + s * 8192 + q * 4096 + wid * 512]);
    }
  };

  f32x4 acc[2][4][2][2];   // [qm][mf][qn][nf]
  #pragma unroll
  for (int a = 0; a < 2; ++a)
    #pragma unroll
    for (int b = 0; b < 4; ++b)
      #pragma unroll
      for (int c = 0; c < 2; ++c)
        #pragma unroll
        for (int d = 0; d < 2; ++d) acc[a][b][c][d] = (f32x4){0.f, 0.f, 0.f, 0.f};

#define LOADA(BUF, S) do { _Pragma("unroll") \
  for (int mf = 0; mf < 4; ++mf) { \
    int ia = (BUF) * 16384 + ((S) * 128 + wm * 64 + mf * 16 + l15) * 64 + colS0; \
    af[mf][0] = *(const bf16x8*)&As[ia]; \
    af[mf][1] = *(const bf16x8*)&As[ia ^ 32]; } } while (0)
#define LOADB(BUF, S, BV) do { _Pragma("unroll") \
  for (int nf = 0; nf < 2; ++nf) { \
    int ib = (BUF) * 16384 + ((S) * 128 + wn * 32 + nf * 16 + l15) * 64 + colS0; \
    BV[nf][0] = *(const bf16x8*)&Bs[ib]; \
    BV[nf][1] = *(const bf16x8*)&Bs[ib ^ 32]; } } while (0)
#define MM(QM, QN, BV) do { __builtin_amdgcn_s_setprio(1); _Pragma("unroll") \
  for (int mf = 0; mf < 4; ++mf) _Pragma("unroll") \
    for (int nf = 0; nf < 2; ++nf) { \
      acc[QM][mf][QN][nf] = __builtin_amdgcn_mfma_f32_16x16x32_bf16( \
          af[mf][0], BV[nf][0], acc[QM][mf][QN][nf], 0, 0, 0); \
      acc[QM][mf][QN][nf] = __builtin_amdgcn_mfma_f32_16x16x32_bf16( \
          af[mf][1], BV[nf][1], acc[QM][mf][QN][nf], 0, 0, 0); } \
  __builtin_amdgcn_s_setprio(0); } while (0)

  // Prologue: fully stage buf0<-K0 and buf1<-K1 (16 loads/wave). GATE(8): buf0 landed.
  stageA(0, 0, 0); stageB(0, 0, 0); stageA(0, 1, 0); stageB(0, 1, 0);
  stageA(1, 0, 1); stageB(1, 0, 1); stageA(1, 1, 1); stageB(1, 1, 1);
  GATE(8);

  bf16x8 af[4][2], bv0[2][2], bv1[2][2];
  const int NITER = NKT >> 1;
  for (int it = 0; it < NITER - 1; ++it) {
    int T = 2 * it;
    // ---- buf0 = tile T ----
    LOADA(0, 0); LOADB(0, 0, bv0);                    BAR2(); MM(0, 0, bv0); BAR2();
    LOADB(0, 1, bv1); stageA(0, 0, T + 2);            BAR2(); MM(0, 1, bv1); BAR2();
    LOADA(0, 1);      stageB(0, 0, T + 2);            BAR2(); MM(1, 1, bv1); BAR2();
    stageA(0, 1, T + 2); stageB(0, 1, T + 2);         BAR2(); MM(1, 0, bv0); GATE(8); // buf1@T+1 landed
    // ---- buf1 = tile T+1 ----
    LOADA(1, 0); LOADB(1, 0, bv0);                    BAR2(); MM(0, 0, bv0); BAR2();
    LOADB(1, 1, bv1); stageA(1, 0, T + 3);            BAR2(); MM(0, 1, bv1); BAR2();
    LOADA(1, 1);      stageB(1, 0, T + 3);            BAR2(); MM(1, 1, bv1); BAR2();
    stageA(1, 1, T + 3); stageB(1, 1, T + 3);         BAR2(); MM(1, 0, bv0); GATE(8); // buf0@T+2 landed
  }
  // ---- peeled tail: tiles NKT-2 (buf0), NKT-1 (buf1); no staging ----
  LOADA(0, 0); LOADB(0, 0, bv0);   BAR2(); MM(0, 0, bv0); BAR2();
  LOADB(0, 1, bv1);                BAR2(); MM(0, 1, bv1); BAR2();
  LOADA(0, 1);                     BAR2(); MM(1, 1, bv1); BAR2();
                                   BAR2(); MM(1, 0, bv0); GATE(0); // buf1@NKT-1 landed
  LOADA(1, 0); LOADB(1, 0, bv0);   BAR2(); MM(0, 0, bv0); BAR2();
  LOADB(1, 1, bv1);                BAR2(); MM(0, 1, bv1); BAR2();
  LOADA(1, 1);                     BAR2(); MM(1, 1, bv1); BAR2();
                                   BAR2(); MM(1, 0, bv0);
#undef LOADA
#undef LOADB
#undef MM

  // Epilogue
  int r0 = bm * 256 + wm * 128, c0 = bn * 256 + wn * 64;
  #pragma unroll
  for (int qm = 0; qm < 2; ++qm)
    #pragma unroll
    for (int mf = 0; mf < 4; ++mf)
      #pragma unroll
      for (int qn = 0; qn < 2; ++qn)
        #pragma unroll
        for (int nf = 0; nf < 2; ++nf) {
          int col = c0 + qn * 32 + nf * 16 + l15;
          #pragma unroll
          for (int r = 0; r < 4; ++r) {
            int row = r0 + qm * 64 + mf * 16 + hi * 4 + r;
            float v = acc[qm][mf][qn][nf][r];
            if (EPI == 0) {
              if (col < 1536) v = (v > 0.f) ? v + 1.f : __expf(v);  // elu(x)+1
              Cb[(size_t)row * N + col] = f2bf(v);
            } else {
              Cf[(size_t)row * N + col] = v + resid[(size_t)row * N + col];
            }
          }
        }
}

// ---------------- kv aggregation: per (b,h) partial kv[96][96] + ksum[96] ----------------
__global__ __launch_bounds__(256) void kvagg_kernel(
    const unsigned short* __restrict__ qkv,
    float* __restrict__ kvp, float* __restrict__ ksump) {
  __shared__ unsigned short KT[96][136];
  __shared__ unsigned short VT[96][136];
  int bh = blockIdx.x >> 3, chunk = blockIdx.x & 7;
  int b = bh >> 3, h = bh & 7;
  int wave = threadIdx.x >> 6, lane = threadIdx.x & 63;
  int wm = wave >> 1, wn = wave & 1;
  size_t rowbase = (size_t)b * SEQ;
  int ck = D_MODEL + h * DH, cv = 2 * D_MODEL + h * DH;
  f32x4 zero = {0.f, 0.f, 0.f, 0.f};
  f32x4 acc[3][3];
  #pragma unroll
  for (int i = 0; i < 3; ++i)
    #pragma unroll
    for (int j = 0; j < 3; ++j) acc[i][j] = zero;
  float ks = 0.f;

  for (int s = 0; s < 4; ++s) {
    int l0 = chunk * 512 + s * 128;
    if (s) __syncthreads();
    #pragma unroll
    for (int i = 0; i < 6; ++i) {
      int idx = i * 256 + threadIdx.x;   // 0..1535
      int l = idx / 12, oc = idx % 12;
      size_t g = (rowbase + l0 + l) * N3;
      ushort8 kk = *(const ushort8*)(qkv + g + ck + oc * 8);
      ushort8 vv = *(const ushort8*)(qkv + g + cv + oc * 8);
      #pragma unroll
      for (int j = 0; j < 8; ++j) { KT[oc * 8 + j][l] = kk[j]; VT[oc * 8 + j][l] = vv[j]; }
    }
    __syncthreads();
    if (threadIdx.x < 96) {
      #pragma unroll 8
      for (int l = 0; l < 128; ++l) ks += bf2f(KT[threadIdx.x][l]);
    }
    #pragma unroll
    for (int kq = 0; kq < 4; ++kq) {
      int k0 = kq * 32 + (lane >> 4) * 8;
      bf16x8 af[3], bfv[3];
      #pragma unroll
      for (int i = 0; i < 3; ++i) af[i]  = *(const bf16x8*)&KT[wm * 48 + i * 16 + (lane & 15)][k0];
      #pragma unroll
      for (int j = 0; j < 3; ++j) bfv[j] = *(const bf16x8*)&VT[wn * 48 + j * 16 + (lane & 15)][k0];
      #pragma unroll
      for (int i = 0; i < 3; ++i)
        #pragma unroll
        for (int j = 0; j < 3; ++j)
          acc[i][j] = __builtin_amdgcn_mfma_f32_16x16x32_bf16(af[i], bfv[j], acc[i][j], 0, 0, 0);
    }
  }
  float* kvpp = kvp + (size_t)blockIdx.x * (96 * 96);
  #pragma unroll
  for (int i = 0; i < 3; ++i)
    #pragma unroll
    for (int j = 0; j < 3; ++j)
      #pragma unroll
      for (int r = 0; r < 4; ++r) {
        int d = wm * 48 + i * 16 + (lane >> 4) * 4 + r;
        int e = wn * 48 + j * 16 + (lane & 15);
        kvpp[d * 96 + e] = acc[i][j][r];
      }
  if (threadIdx.x < 96) ksump[(size_t)blockIdx.x * 96 + threadIdx.x] = ks;
}

// ---------------- reduce 8 partials -> kvT bf16 [64][112][96] ----------------
__global__ __launch_bounds__(256) void kvreduce_kernel(
    const float* __restrict__ kvp, const float* __restrict__ ksump,
    unsigned short* __restrict__ kvT) {
  int idx = blockIdx.x * 256 + threadIdx.x;
  if (idx >= 64 * 112 * 96) return;
  int d = idx % 96;
  int e = (idx / 96) % 112;
  int bh = idx / (96 * 112);
  float s = 0.f;
  if (e < 96) {
    #pragma unroll
    for (int c = 0; c < 8; ++c) s += kvp[(((size_t)bh * 8 + c) * 96 + d) * 96 + e];
  } else if (e == 96) {
    #pragma unroll
    for (int c = 0; c < 8; ++c) s += ksump[((size_t)bh * 8 + c) * 96 + d];
  }
  kvT[idx] = f2bf(s);
}

// ---------------- readout ----------------
__global__ __launch_bounds__(256) void readout_kernel(
    const unsigned short* __restrict__ qkv, const unsigned short* __restrict__ kvT,
    unsigned short* __restrict__ attn) {
  __shared__ unsigned short Qs[128][104];
  __shared__ unsigned short Ks[112][104];
  int bh = blockIdx.x >> 5, lc = blockIdx.x & 31;
  int b = bh >> 3, h = bh & 7;
  int l0 = lc * 128;
  int wave = threadIdx.x >> 6, lane = threadIdx.x & 63;
  #pragma unroll
  for (int i = 0; i < 6; ++i) {
    int idx = i * 256 + threadIdx.x;   // 0..1535
    int l = idx / 12, oc = idx % 12;
    size_t g = ((size_t)b * SEQ + l0 + l) * N3 + h * DH + oc * 8;
    *(ushort8*)&Qs[l][oc * 8] = *(const ushort8*)(qkv + g);
  }
  const unsigned short* kvbh = kvT + (size_t)bh * 112 * 96;
  #pragma unroll
  for (int i = 0; i < 6; ++i) {
    int idx = i * 256 + threadIdx.x;
    if (idx < 1344) {
      int e = idx / 12, oc = idx % 12;
      *(ushort8*)&Ks[e][oc * 8] = *(const ushort8*)(kvbh + e * 96 + oc * 8);
    }
  }
  __syncthreads();
  f32x4 zero = {0.f, 0.f, 0.f, 0.f};
  f32x4 acc[2][7];
  #pragma unroll
  for (int i = 0; i < 2; ++i)
    #pragma unroll
    for (int j = 0; j < 7; ++j) acc[i][j] = zero;
  #pragma unroll
  for (int kq = 0; kq < 3; ++kq) {
    int k0 = kq * 32 + (lane >> 4) * 8;
    bf16x8 af[2], bfv[7];
    #pragma unroll
    for (int i = 0; i < 2; ++i) af[i]  = *(const bf16x8*)&Qs[wave * 32 + i * 16 + (lane & 15)][k0];
    #pragma unroll
    for (int j = 0; j < 7; ++j) bfv[j] = *(const bf16x8*)&Ks[j * 16 + (lane & 15)][k0];
    #pragma unroll
    for (int i = 0; i < 2; ++i)
      #pragma unroll
      for (int j = 0; j < 7; ++j)
        acc[i][j] = __builtin_amdgcn_mfma_f32_16x16x32_bf16(af[i], bfv[j], acc[i][j], 0, 0, 0);
  }
  int g4 = lane >> 4;
  #pragma unroll
  for (int i = 0; i < 2; ++i) {
    #pragma unroll
    for (int r = 0; r < 4; ++r) {
      float nv = __shfl(acc[i][6][r], lane & 48, 64);   // col 96 value for this row
      float inv = 1.f / fmaxf(nv, 1e-6f);
      size_t orow = (size_t)b * SEQ + l0 + wave * 32 + i * 16 + g4 * 4 + r;
      #pragma unroll
      for (int j = 0; j < 6; ++j) {
        int col = h * DH + j * 16 + (lane & 15);
        attn[orow * D_MODEL + col] = f2bf(acc[i][j][r] * inv);
      }
    }
  }
}

extern "C" void kernel_launch(void* const* d_in, const int* in_sizes, int n_in,
                              void* d_out, int out_size, void* d_ws, size_t ws_size,
                              hipStream_t stream) {
  const float* x     = (const float*)d_in[0];
  const float* gamma = (const float*)d_in[1];
  const float* beta  = (const float*)d_in[2];
  const float* w_qkv = (const float*)d_in[3];
  const float* w_out = (const float*)d_in[4];
  float* out = (float*)d_out;

  char* ws = (char*)d_ws;
  size_t off = 0;
  auto alloc = [&](size_t bytes) -> void* {
    void* p = ws + off; off += (bytes + 255) & ~(size_t)255; return p;
  };
  unsigned short* xn    = (unsigned short*)alloc((size_t)ROWS * D_MODEL * 2);  // reused as attn
  unsigned short* qkv   = (unsigned short*)alloc((size_t)ROWS * N3 * 2);
  unsigned short* wqkvT = (unsigned short*)alloc((size_t)N3 * D_MODEL * 2);
  unsigned short* woutT = (unsigned short*)alloc((size_t)D_MODEL * D_MODEL * 2);
  float* kvp            = (float*)alloc((size_t)512 * 96 * 96 * 4);
  float* ksump          = (float*)alloc((size_t)512 * 96 * 4);
  unsigned short* kvT   = (unsigned short*)alloc((size_t)64 * 112 * 96 * 2);

  transpose_cast_kernel<<<dim3(N3 / 32, D_MODEL / 32), 256, 0, stream>>>(w_qkv, wqkvT, D_MODEL, N3);
  transpose_cast_kernel<<<dim3(D_MODEL / 32, D_MODEL / 32), 256, 0, stream>>>(w_out, woutT, D_MODEL, D_MODEL);
  ln_kernel<<<ROWS / 4, 256, 0, stream>>>(x, gamma, beta, xn);
  gemm2_kernel<0><<<(ROWS / 256) * (N3 / 256), 512, 0, stream>>>(
      xn, wqkvT, ROWS, N3, D_MODEL, N3 / 256, qkv, nullptr, nullptr);
  kvagg_kernel<<<512, 256, 0, stream>>>(qkv, kvp, ksump);
  kvreduce_kernel<<<(64 * 112 * 96 + 255) / 256, 256, 0, stream>>>(kvp, ksump, kvT);
  readout_kernel<<<2048, 256, 0, stream>>>(qkv, kvT, xn);  // attn overwrites xn
  gemm2_kernel<1><<<(ROWS / 256) * (D_MODEL / 256), 512, 0, stream>>>(
      xn, woutT, ROWS, D_MODEL, D_MODEL, D_MODEL / 256, nullptr, x, out);
}

// Round 4
// 366.514 us; speedup vs baseline: 1.2154x; 1.0693x over previous
//
#include <hip/hip_runtime.h>
#include <stdint.h>

#define D_MODEL 768
#define N3      2304
#define NHEAD   8
#define DH      96
#define BATCH   8
#define SEQ     4096
#define ROWS    (BATCH*SEQ)   // 32768
#define LN_EPS  1e-5f

typedef __attribute__((ext_vector_type(8))) __bf16 bf16x8;
typedef __attribute__((ext_vector_type(4))) float f32x4;
typedef __attribute__((ext_vector_type(8))) unsigned short ushort8;
typedef __attribute__((ext_vector_type(4))) unsigned short ushort4v;

__device__ __forceinline__ unsigned short f2bf(float f) {
  union { float f; unsigned int u; } v; v.f = f;
  unsigned int r = v.u + 0x7FFFu + ((v.u >> 16) & 1u);
  return (unsigned short)(r >> 16);
}
__device__ __forceinline__ float bf2f(unsigned short u) {
  union { unsigned int u; float f; } v; v.u = ((unsigned int)u) << 16;
  return v.f;
}

#define GLOBAL_LDS16(src, dst) \
  __builtin_amdgcn_global_load_lds((const __attribute__((address_space(1))) void*)(src), \
                                   (__attribute__((address_space(3))) void*)(dst), 16, 0, 0)

#define GATE(n) do { asm volatile("s_waitcnt vmcnt(" #n ")" ::: "memory"); \
                     __builtin_amdgcn_s_barrier(); asm volatile("" ::: "memory"); } while (0)

// ---------------- transpose + cast fp32[R][C] -> bf16[C][R] ----------------
__global__ __launch_bounds__(256) void transpose_cast_kernel(
    const float* __restrict__ in, unsigned short* __restrict__ out, int R, int C) {
  __shared__ float tile[32][33];
  int c0 = blockIdx.x * 32, r0 = blockIdx.y * 32;
  int tx = threadIdx.x & 31, ty = threadIdx.x >> 5;
  #pragma unroll
  for (int i = ty; i < 32; i += 8)
    tile[i][tx] = in[(size_t)(r0 + i) * C + c0 + tx];
  __syncthreads();
  #pragma unroll
  for (int i = ty; i < 32; i += 8)
    out[(size_t)(c0 + i) * R + r0 + tx] = f2bf(tile[tx][i]);
}

// ---------------- LayerNorm: fp32 in -> bf16 out, one wave per row ----------------
__global__ __launch_bounds__(256) void ln_kernel(
    const float* __restrict__ x, const float* __restrict__ gamma,
    const float* __restrict__ beta, unsigned short* __restrict__ xn) {
  int wave = threadIdx.x >> 6, lane = threadIdx.x & 63;
  int row = blockIdx.x * 4 + wave;
  const float* xr = x + (size_t)row * D_MODEL;
  f32x4 v[3];
  float s = 0.f, sq = 0.f;
  #pragma unroll
  for (int i = 0; i < 3; ++i) {
    v[i] = *(const f32x4*)(xr + (i * 64 + lane) * 4);
    #pragma unroll
    for (int c = 0; c < 4; ++c) { s += v[i][c]; sq += v[i][c] * v[i][c]; }
  }
  #pragma unroll
  for (int o = 32; o; o >>= 1) {
    s  += __shfl_xor(s, o, 64);
    sq += __shfl_xor(sq, o, 64);
  }
  float mu  = s * (1.f / 768.f);
  float var = sq * (1.f / 768.f) - mu * mu;
  float rs  = rsqrtf(var + LN_EPS);
  #pragma unroll
  for (int i = 0; i < 3; ++i) {
    int col = (i * 64 + lane) * 4;
    ushort4v o;
    #pragma unroll
    for (int c = 0; c < 4; ++c)
      o[c] = f2bf((v[i][c] - mu) * rs * gamma[col + c] + beta[col + c]);
    *(ushort4v*)(xn + (size_t)row * D_MODEL + col) = o;
  }
}

// ======== GEMM 256x256, BK=32, 3 LDS buffers, ONE barrier per K-tile ========
// C[M][N] = A[M][K] @ Bt[N][K]^T.  EPI 0: elu+1 on cols<1536, bf16 out.
// EPI 1: +residual, fp32 out.   Requires K % 96 == 0 (NKT = K/32 mult of 3).
// Tile T uses buf T%3; stage for T+2 writes buf (T-1)%3 which is DEAD during
// tiles T..T+1 -> no intra-tile barriers. Gate at tile top: GATE(4) proves
// tile T landed (FIFO vmcnt, 4 loads/wave/tile); final tile GATE(0).
// Swizzle: phys 16B-slot = logical ^ ((row>>1)&3), same involution on the
// pre-swizzled global source, so reads recover logical slot hi.
template <int EPI>
__global__ __launch_bounds__(512, 2) void gemm3_kernel(
    const unsigned short* __restrict__ A, const unsigned short* __restrict__ Bt,
    int M, int N, int K, int nbn,
    unsigned short* __restrict__ Cb, const float* __restrict__ resid,
    float* __restrict__ Cf) {
  __shared__ unsigned short As[3 * 8192];  // [buf][row 256][k 32]
  __shared__ unsigned short Bs[3 * 8192];

  const int NKT = K >> 5;
  int nwg = gridDim.x, id = blockIdx.x;
  int q8 = nwg >> 3;
  int wg = (id & 7) * q8 + (id >> 3);
  int bm = wg / nbn, bn = wg % nbn;

  const int lane = threadIdx.x & 63, wid = threadIdx.x >> 6;
  const int wm = wid >> 2, wn = wid & 3;
  const int l15 = lane & 15, hi = lane >> 4;
  const int colS = (hi ^ ((l15 >> 1) & 3)) << 3;
  const int srow = lane >> 2;
  const int scol = ((lane & 3) ^ ((lane >> 3) & 3)) << 3;

  auto stage = [&](unsigned short* dstBase, const unsigned short* G, int bOff,
                   int buf, int kt) {
    #pragma unroll
    for (int q = 0; q < 2; ++q) {
      const unsigned short* src =
          G + (size_t)(bOff * 256 + q * 128 + wid * 16 + srow) * K + kt * 32 + scol;
      GLOBAL_LDS16(src, dstBase + buf * 8192 + q * 4096 + wid * 512);
    }
  };

  f32x4 acc[8][4];   // rows wm*128+mf*16+hi*4+r, cols wn*64+nf*16+l15
  #pragma unroll
  for (int i = 0; i < 8; ++i)
    #pragma unroll
    for (int j = 0; j < 4; ++j) acc[i][j] = (f32x4){0.f, 0.f, 0.f, 0.f};

#define TILE(BUF, STG) do { \
    bf16x8 af[8], bv[4]; \
    _Pragma("unroll") for (int mf = 0; mf < 8; ++mf) \
      af[mf] = *(const bf16x8*)&As[(BUF) * 8192 + (wm * 128 + mf * 16 + l15) * 32 + colS]; \
    _Pragma("unroll") for (int nf = 0; nf < 4; ++nf) \
      bv[nf] = *(const bf16x8*)&Bs[(BUF) * 8192 + (wn * 64 + nf * 16 + l15) * 32 + colS]; \
    STG; \
    __builtin_amdgcn_s_setprio(1); \
    _Pragma("unroll") for (int mf = 0; mf < 8; ++mf) \
      _Pragma("unroll") for (int nf = 0; nf < 4; ++nf) \
        acc[mf][nf] = __builtin_amdgcn_mfma_f32_16x16x32_bf16( \
            af[mf], bv[nf], acc[mf][nf], 0, 0, 0); \
    __builtin_amdgcn_s_setprio(0); \
  } while (0)

  // Prologue: stage tiles 0 (buf0) and 1 (buf1): 8 loads/wave in flight.
  stage(As, A, bm, 0, 0); stage(Bs, Bt, bn, 0, 0);
  stage(As, A, bm, 1, 1); stage(Bs, Bt, bn, 1, 1);

  const int NITER3 = NKT / 3;
  for (int it = 0; it < NITER3 - 1; ++it) {
    int T = 3 * it;
    GATE(4); TILE(0, { stage(As, A, bm, 2, T + 2); stage(Bs, Bt, bn, 2, T + 2); });
    GATE(4); TILE(1, { stage(As, A, bm, 0, T + 3); stage(Bs, Bt, bn, 0, T + 3); });
    GATE(4); TILE(2, { stage(As, A, bm, 1, T + 4); stage(Bs, Bt, bn, 1, T + 4); });
  }
  // Peeled tail: tiles NKT-3 (buf0, stages NKT-1), NKT-2 (buf1), NKT-1 (buf2).
  GATE(4); TILE(0, { stage(As, A, bm, 2, NKT - 1); stage(Bs, Bt, bn, 2, NKT - 1); });
  GATE(4); TILE(1, {});
  GATE(0); TILE(2, {});
#undef TILE

  // Epilogue
  int r0 = bm * 256 + wm * 128, c0 = bn * 256 + wn * 64;
  #pragma unroll
  for (int mf = 0; mf < 8; ++mf)
    #pragma unroll
    for (int nf = 0; nf < 4; ++nf) {
      int col = c0 + nf * 16 + l15;
      #pragma unroll
      for (int r = 0; r < 4; ++r) {
        int row = r0 + mf * 16 + hi * 4 + r;
        float v = acc[mf][nf][r];
        if (EPI == 0) {
          if (col < 1536) v = (v > 0.f) ? v + 1.f : __expf(v);  // elu(x)+1
          Cb[(size_t)row * N + col] = f2bf(v);
        } else {
          Cf[(size_t)row * N + col] = v + resid[(size_t)row * N + col];
        }
      }
    }
}

// ---------------- kv aggregation: per (b,h) partial kv[96][96] + ksum[96] ----------------
__global__ __launch_bounds__(256) void kvagg_kernel(
    const unsigned short* __restrict__ qkv,
    float* __restrict__ kvp, float* __restrict__ ksump) {
  __shared__ unsigned short KT[96][136];
  __shared__ unsigned short VT[96][136];
  int bh = blockIdx.x >> 3, chunk = blockIdx.x & 7;
  int b = bh >> 3, h = bh & 7;
  int wave = threadIdx.x >> 6, lane = threadIdx.x & 63;
  int wm = wave >> 1, wn = wave & 1;
  size_t rowbase = (size_t)b * SEQ;
  int ck = D_MODEL + h * DH, cv = 2 * D_MODEL + h * DH;
  f32x4 zero = {0.f, 0.f, 0.f, 0.f};
  f32x4 acc[3][3];
  #pragma unroll
  for (int i = 0; i < 3; ++i)
    #pragma unroll
    for (int j = 0; j < 3; ++j) acc[i][j] = zero;
  float ks = 0.f;

  for (int s = 0; s < 4; ++s) {
    int l0 = chunk * 512 + s * 128;
    if (s) __syncthreads();
    #pragma unroll
    for (int i = 0; i < 6; ++i) {
      int idx = i * 256 + threadIdx.x;   // 0..1535
      int l = idx / 12, oc = idx % 12;
      size_t g = (rowbase + l0 + l) * N3;
      ushort8 kk = *(const ushort8*)(qkv + g + ck + oc * 8);
      ushort8 vv = *(const ushort8*)(qkv + g + cv + oc * 8);
      #pragma unroll
      for (int j = 0; j < 8; ++j) { KT[oc * 8 + j][l] = kk[j]; VT[oc * 8 + j][l] = vv[j]; }
    }
    __syncthreads();
    if (threadIdx.x < 96) {
      #pragma unroll 8
      for (int l = 0; l < 128; ++l) ks += bf2f(KT[threadIdx.x][l]);
    }
    #pragma unroll
    for (int kq = 0; kq < 4; ++kq) {
      int k0 = kq * 32 + (lane >> 4) * 8;
      bf16x8 af[3], bfv[3];
      #pragma unroll
      for (int i = 0; i < 3; ++i) af[i]  = *(const bf16x8*)&KT[wm * 48 + i * 16 + (lane & 15)][k0];
      #pragma unroll
      for (int j = 0; j < 3; ++j) bfv[j] = *(const bf16x8*)&VT[wn * 48 + j * 16 + (lane & 15)][k0];
      #pragma unroll
      for (int i = 0; i < 3; ++i)
        #pragma unroll
        for (int j = 0; j < 3; ++j)
          acc[i][j] = __builtin_amdgcn_mfma_f32_16x16x32_bf16(af[i], bfv[j], acc[i][j], 0, 0, 0);
    }
  }
  float* kvpp = kvp + (size_t)blockIdx.x * (96 * 96);
  #pragma unroll
  for (int i = 0; i < 3; ++i)
    #pragma unroll
    for (int j = 0; j < 3; ++j)
      #pragma unroll
      for (int r = 0; r < 4; ++r) {
        int d = wm * 48 + i * 16 + (lane >> 4) * 4 + r;
        int e = wn * 48 + j * 16 + (lane & 15);
        kvpp[d * 96 + e] = acc[i][j][r];
      }
  if (threadIdx.x < 96) ksump[(size_t)blockIdx.x * 96 + threadIdx.x] = ks;
}

// ---------------- reduce 8 partials -> kvT bf16 [64][112][96] ----------------
__global__ __launch_bounds__(256) void kvreduce_kernel(
    const float* __restrict__ kvp, const float* __restrict__ ksump,
    unsigned short* __restrict__ kvT) {
  int idx = blockIdx.x * 256 + threadIdx.x;
  if (idx >= 64 * 112 * 96) return;
  int d = idx % 96;
  int e = (idx / 96) % 112;
  int bh = idx / (96 * 112);
  float s = 0.f;
  if (e < 96) {
    #pragma unroll
    for (int c = 0; c < 8; ++c) s += kvp[(((size_t)bh * 8 + c) * 96 + d) * 96 + e];
  } else if (e == 96) {
    #pragma unroll
    for (int c = 0; c < 8; ++c) s += ksump[((size_t)bh * 8 + c) * 96 + d];
  }
  kvT[idx] = f2bf(s);
}

// ---------------- readout ----------------
__global__ __launch_bounds__(256) void readout_kernel(
    const unsigned short* __restrict__ qkv, const unsigned short* __restrict__ kvT,
    unsigned short* __restrict__ attn) {
  __shared__ unsigned short Qs[128][104];
  __shared__ unsigned short Ks[112][104];
  int bh = blockIdx.x >> 5, lc = blockIdx.x & 31;
  int b = bh >> 3, h = bh & 7;
  int l0 = lc * 128;
  int wave = threadIdx.x >> 6, lane = threadIdx.x & 63;
  #pragma unroll
  for (int i = 0; i < 6; ++i) {
    int idx = i * 256 + threadIdx.x;   // 0..1535
    int l = idx / 12, oc = idx % 12;
    size_t g = ((size_t)b * SEQ + l0 + l) * N3 + h * DH + oc * 8;
    *(ushort8*)&Qs[l][oc * 8] = *(const ushort8*)(qkv + g);
  }
  const unsigned short* kvbh = kvT + (size_t)bh * 112 * 96;
  #pragma unroll
  for (int i = 0; i < 6; ++i) {
    int idx = i * 256 + threadIdx.x;
    if (idx < 1344) {
      int e = idx / 12, oc = idx % 12;
      *(ushort8*)&Ks[e][oc * 8] = *(const ushort8*)(kvbh + e * 96 + oc * 8);
    }
  }
  __syncthreads();
  f32x4 zero = {0.f, 0.f, 0.f, 0.f};
  f32x4 acc[2][7];
  #pragma unroll
  for (int i = 0; i < 2; ++i)
    #pragma unroll
    for (int j = 0; j < 7; ++j) acc[i][j] = zero;
  #pragma unroll
  for (int kq = 0; kq < 3; ++kq) {
    int k0 = kq * 32 + (lane >> 4) * 8;
    bf16x8 af[2], bfv[7];
    #pragma unroll
    for (int i = 0; i < 2; ++i) af[i]  = *(const bf16x8*)&Qs[wave * 32 + i * 16 + (lane & 15)][k0];
    #pragma unroll
    for (int j = 0; j < 7; ++j) bfv[j] = *(const bf16x8*)&Ks[j * 16 + (lane & 15)][k0];
    #pragma unroll
    for (int i = 0; i < 2; ++i)
      #pragma unroll
      for (int j = 0; j < 7; ++j)
        acc[i][j] = __builtin_amdgcn_mfma_f32_16x16x32_bf16(af[i], bfv[j], acc[i][j], 0, 0, 0);
  }
  int g4 = lane >> 4;
  #pragma unroll
  for (int i = 0; i < 2; ++i) {
    #pragma unroll
    for (int r = 0; r < 4; ++r) {
      float nv = __shfl(acc[i][6][r], lane & 48, 64);   // col 96 value for this row
      float inv = 1.f / fmaxf(nv, 1e-6f);
      size_t orow = (size_t)b * SEQ + l0 + wave * 32 + i * 16 + g4 * 4 + r;
      #pragma unroll
      for (int j = 0; j < 6; ++j) {
        int col = h * DH + j * 16 + (lane & 15);
        attn[orow * D_MODEL + col] = f2bf(acc[i][j][r] * inv);
      }
    }
  }
}

extern "C" void kernel_launch(void* const* d_in, const int* in_sizes, int n_in,
                              void* d_out, int out_size, void* d_ws, size_t ws_size,
                              hipStream_t stream) {
  const float* x     = (const float*)d_in[0];
  const float* gamma = (const float*)d_in[1];
  const float* beta  = (const float*)d_in[2];
  const float* w_qkv = (const float*)d_in[3];
  const float* w_out = (const float*)d_in[4];
  float* out = (float*)d_out;

  char* ws = (char*)d_ws;
  size_t off = 0;
  auto alloc = [&](size_t bytes) -> void* {
    void* p = ws + off; off += (bytes + 255) & ~(size_t)255; return p;
  };
  unsigned short* xn    = (unsigned short*)alloc((size_t)ROWS * D_MODEL * 2);  // reused as attn
  unsigned short* qkv   = (unsigned short*)alloc((size_t)ROWS * N3 * 2);
  unsigned short* wqkvT = (unsigned short*)alloc((size_t)N3 * D_MODEL * 2);
  unsigned short* woutT = (unsigned short*)alloc((size_t)D_MODEL * D_MODEL * 2);
  float* kvp            = (float*)alloc((size_t)512 * 96 * 96 * 4);
  float* ksump          = (float*)alloc((size_t)512 * 96 * 4);
  unsigned short* kvT   = (unsigned short*)alloc((size_t)64 * 112 * 96 * 2);

  transpose_cast_kernel<<<dim3(N3 / 32, D_MODEL / 32), 256, 0, stream>>>(w_qkv, wqkvT, D_MODEL, N3);
  transpose_cast_kernel<<<dim3(D_MODEL / 32, D_MODEL / 32), 256, 0, stream>>>(w_out, woutT, D_MODEL, D_MODEL);
  ln_kernel<<<ROWS / 4, 256, 0, stream>>>(x, gamma, beta, xn);
  gemm3_kernel<0><<<(ROWS / 256) * (N3 / 256), 512, 0, stream>>>(
      xn, wqkvT, ROWS, N3, D_MODEL, N3 / 256, qkv, nullptr, nullptr);
  kvagg_kernel<<<512, 256, 0, stream>>>(qkv, kvp, ksump);
  kvreduce_kernel<<<(64 * 112 * 96 + 255) / 256, 256, 0, stream>>>(kvp, ksump, kvT);
  readout_kernel<<<2048, 256, 0, stream>>>(qkv, kvT, xn);  // attn overwrites xn
  gemm3_kernel<1><<<(ROWS / 256) * (D_MODEL / 256), 512, 0, stream>>>(
      xn, woutT, ROWS, D_MODEL, D_MODEL, D_MODEL / 256, nullptr, x, out);
}